// Round 1
// baseline (1712.159 us; speedup 1.0000x reference)
//
#include <hip/hip_runtime.h>
#include <hip/hip_bf16.h>
#include <hip/hip_fp8.h>

typedef __attribute__((ext_vector_type(8))) short short8;
typedef __attribute__((ext_vector_type(4))) float f32x4;

#define AS1 __attribute__((address_space(1)))
#define AS3 __attribute__((address_space(3)))

static constexpr int Mdim = 4096;
static constexpr int Kdim = 7168;
static constexpr int Ndim = 16384;
static constexpr float FP8_MAX = 448.0f;

__device__ __forceinline__ void gload_lds16(const void* g, void* l) {
    // async global->LDS, 16B per lane; LDS dest = wave-uniform base + lane*16
    __builtin_amdgcn_global_load_lds((const AS1 void*)g, (AS3 void*)l, 16, 0, 0);
}

// ---------------------------------------------------------------------------
// Kernel 1: activation quant  x[M,K] f32 -> xdq[M,K] bf16
// per (1x128) block: s = amax/448; xdq = bf16( f32(fp8_rne(x/s)) * s )
// one wave per 128-block, 2 f32 per lane
// ---------------------------------------------------------------------------
__global__ __launch_bounds__(256) void quant_x_kernel(
    const float* __restrict__ x, __hip_bfloat16* __restrict__ xdq)
{
    constexpr int NBLK = Mdim * (Kdim / 128);  // 229376
    const int lane = threadIdx.x & 63;
    const int wid  = (blockIdx.x * 256 + threadIdx.x) >> 6;
    const int nw   = (gridDim.x * 256) >> 6;

    for (int b = wid; b < NBLK; b += nw) {
        size_t base = (size_t)b * 128 + lane * 2;
        float2 v = *reinterpret_cast<const float2*>(x + base);
        float amax = fmaxf(fabsf(v.x), fabsf(v.y));
#pragma unroll
        for (int off = 32; off > 0; off >>= 1)
            amax = fmaxf(amax, __shfl_xor(amax, off));
        float s = amax * (1.0f / FP8_MAX);
        float q0 = 0.0f, q1 = 0.0f;
        if (s > 0.0f) {  // wave-uniform branch
            q0 = (float)__hip_fp8_e4m3(v.x / s) * s;
            q1 = (float)__hip_fp8_e4m3(v.y / s) * s;
        }
        __hip_bfloat162 o;
        o.x = __float2bfloat16(q0);
        o.y = __float2bfloat16(q1);
        *reinterpret_cast<__hip_bfloat162*>(xdq + base) = o;
    }
}

// ---------------------------------------------------------------------------
// Kernel 2: weight quant  w[N,K] f32 -> wdq[N,K] bf16
// wdq = bf16( f32(fp8_rne(w)) * ws[n/128, k/128] ), 8 elems per thread
// ---------------------------------------------------------------------------
__global__ __launch_bounds__(256) void quant_w_kernel(
    const float* __restrict__ w, const float* __restrict__ ws,
    __hip_bfloat16* __restrict__ wdq)
{
    constexpr size_t NCHUNK = (size_t)Ndim * Kdim / 8;  // 14.68M
    constexpr int CPR = Kdim / 8;    // 896 chunks per row
    constexpr int KB  = Kdim / 128;  // 56 scale cols

    size_t idx    = (size_t)blockIdx.x * 256 + threadIdx.x;
    size_t stride = (size_t)gridDim.x * 256;

    for (size_t c = idx; c < NCHUNK; c += stride) {
        int n  = (int)(c / CPR);         // constant divisor -> magic mul
        int kc = (int)(c - (size_t)n * CPR);
        int k  = kc * 8;
        float s = ws[(n >> 7) * KB + (k >> 7)];
        const float* src = w + (size_t)n * Kdim + k;
        float4 v0 = *reinterpret_cast<const float4*>(src);
        float4 v1 = *reinterpret_cast<const float4*>(src + 4);

        __hip_bfloat16 h[8];
        h[0] = __float2bfloat16((float)__hip_fp8_e4m3(v0.x) * s);
        h[1] = __float2bfloat16((float)__hip_fp8_e4m3(v0.y) * s);
        h[2] = __float2bfloat16((float)__hip_fp8_e4m3(v0.z) * s);
        h[3] = __float2bfloat16((float)__hip_fp8_e4m3(v0.w) * s);
        h[4] = __float2bfloat16((float)__hip_fp8_e4m3(v1.x) * s);
        h[5] = __float2bfloat16((float)__hip_fp8_e4m3(v1.y) * s);
        h[6] = __float2bfloat16((float)__hip_fp8_e4m3(v1.z) * s);
        h[7] = __float2bfloat16((float)__hip_fp8_e4m3(v1.w) * s);
        *reinterpret_cast<short8*>(wdq + (size_t)n * Kdim + k) =
            *reinterpret_cast<short8*>(h);
    }
}

// ---------------------------------------------------------------------------
// Kernel 3: NT GEMM  C[M,N] f32 = A[M,K] @ B[N,K]^T   (both bf16, K-major)
// m97 structure: 128x128 tile, BK=32, 4 waves (2x2), 4x4 frags of 16x16x32,
// global_load_lds width 16, 2-barrier K-loop, XCD-bijective blockIdx swizzle
// ---------------------------------------------------------------------------
__global__ __launch_bounds__(256) void gemm_bt_kernel(
    const __hip_bfloat16* __restrict__ A,
    const __hip_bfloat16* __restrict__ B,
    float* __restrict__ C)
{
    constexpr int BM = 128, BN = 128, BK = 32;
    constexpr int NBN = Ndim / BN;           // 128
    constexpr int NWG = (Mdim / BM) * NBN;   // 4096 (%8 == 0)

    __shared__ __align__(16) __hip_bfloat16 ldsA[BM * BK];  // 8 KB
    __shared__ __align__(16) __hip_bfloat16 ldsB[BN * BK];  // 8 KB

    const int tid  = threadIdx.x;
    const int w    = tid >> 6;
    const int lane = tid & 63;
    const int wr   = w >> 1, wc = w & 1;     // wave grid 2x2 -> 64x64 out each
    const int lr   = lane & 15;              // fragment row within 16
    const int lk   = lane >> 4;              // k-group 0..3

    // XCD-aware bijective swizzle (NWG % 8 == 0)
    int bid = (int)blockIdx.x;
    int swz = (bid & 7) * (NWG >> 3) + (bid >> 3);
    const int bm = (swz / NBN) * BM;
    const int bn = (swz % NBN) * BN;

    const __hip_bfloat16* Abase = A + (size_t)bm * Kdim;
    const __hip_bfloat16* Bbase = B + (size_t)bn * Kdim;

    // staging: 512 chunks of 16B per tile, 2 rounds x 256 threads
    const int c0 = w * 64 + lane;    // round-0 chunk
    const int c1 = c0 + 256;         // round-1 chunk
    const int r0 = c0 >> 2, k80 = (c0 & 3) * 8;
    const int r1 = c1 >> 2, k81 = (c1 & 3) * 8;
    __hip_bfloat16* lA0 = &ldsA[(size_t)(w * 64) * 8];
    __hip_bfloat16* lA1 = &ldsA[(size_t)(256 + w * 64) * 8];
    __hip_bfloat16* lB0 = &ldsB[(size_t)(w * 64) * 8];
    __hip_bfloat16* lB1 = &ldsB[(size_t)(256 + w * 64) * 8];

    f32x4 acc[4][4] = {};

    for (int k0 = 0; k0 < Kdim; k0 += BK) {
        gload_lds16(Abase + (size_t)r0 * Kdim + k0 + k80, lA0);
        gload_lds16(Abase + (size_t)r1 * Kdim + k0 + k81, lA1);
        gload_lds16(Bbase + (size_t)r0 * Kdim + k0 + k80, lB0);
        gload_lds16(Bbase + (size_t)r1 * Kdim + k0 + k81, lB1);
        __syncthreads();  // compiler emits vmcnt(0) before s_barrier

        short8 a[4], b[4];
#pragma unroll
        for (int mi = 0; mi < 4; ++mi)
            a[mi] = *reinterpret_cast<const short8*>(
                &ldsA[(wr * 64 + mi * 16 + lr) * BK + lk * 8]);
#pragma unroll
        for (int ni = 0; ni < 4; ++ni)
            b[ni] = *reinterpret_cast<const short8*>(
                &ldsB[(wc * 64 + ni * 16 + lr) * BK + lk * 8]);
#pragma unroll
        for (int mi = 0; mi < 4; ++mi)
#pragma unroll
            for (int ni = 0; ni < 4; ++ni)
                acc[mi][ni] = __builtin_amdgcn_mfma_f32_16x16x32_bf16(
                    a[mi], b[ni], acc[mi][ni], 0, 0, 0);
        __syncthreads();
    }

    // epilogue: C/D layout col = lane&15, row = (lane>>4)*4 + reg
#pragma unroll
    for (int mi = 0; mi < 4; ++mi) {
#pragma unroll
        for (int ni = 0; ni < 4; ++ni) {
#pragma unroll
            for (int j = 0; j < 4; ++j) {
                int row = bm + wr * 64 + mi * 16 + lk * 4 + j;
                int col = bn + wc * 64 + ni * 16 + lr;
                C[(size_t)row * Ndim + col] = acc[mi][ni][j];
            }
        }
    }
}

// ---------------------------------------------------------------------------
extern "C" void kernel_launch(void* const* d_in, const int* in_sizes, int n_in,
                              void* d_out, int out_size, void* d_ws, size_t ws_size,
                              hipStream_t stream) {
    const float* x  = (const float*)d_in[0];       // [M,K]
    const float* w  = (const float*)d_in[1];       // [N,K]
    const float* ws = (const float*)d_in[2];       // [N/128, K/128]

    __hip_bfloat16* xdq = (__hip_bfloat16*)d_ws;                   // 58.7 MB
    __hip_bfloat16* wdq = xdq + (size_t)Mdim * Kdim;               // 234.9 MB

    quant_x_kernel<<<2048, 256, 0, stream>>>(x, xdq);
    quant_w_kernel<<<4096, 256, 0, stream>>>(w, ws, wdq);

    constexpr int NWG = (Mdim / 128) * (Ndim / 128);  // 4096
    gemm_bt_kernel<<<NWG, 256, 0, stream>>>(xdq, wdq, (float*)d_out);
}

// Round 2
// 1040.465 us; speedup vs baseline: 1.6456x; 1.6456x over previous
//
#include <hip/hip_runtime.h>
#include <hip/hip_bf16.h>
#include <hip/hip_fp8.h>

typedef __attribute__((ext_vector_type(8))) short short8;
typedef __attribute__((ext_vector_type(4))) float f32x4;

#define AS1 __attribute__((address_space(1)))
#define AS3 __attribute__((address_space(3)))

static constexpr int Mdim = 4096;
static constexpr int Kdim = 7168;
static constexpr int Ndim = 16384;
static constexpr float FP8_MAX = 448.0f;

// compiler-fence + raw barrier (no implicit vmcnt(0) drain)
#define BARRIER() do { asm volatile("" ::: "memory"); \
                       __builtin_amdgcn_s_barrier();  \
                       asm volatile("" ::: "memory"); } while (0)

#define MFMA_BF16 __builtin_amdgcn_mfma_f32_16x16x32_bf16

// ---------------------------------------------------------------------------
// Kernel 1: activation quant  x[M,K] f32 -> xdq[M,K] bf16 (per 1x128 block)
// ---------------------------------------------------------------------------
__global__ __launch_bounds__(256) void quant_x_kernel(
    const float* __restrict__ x, __hip_bfloat16* __restrict__ xdq)
{
    constexpr int NBLK = Mdim * (Kdim / 128);
    const int lane = threadIdx.x & 63;
    const int wid  = (blockIdx.x * 256 + threadIdx.x) >> 6;
    const int nw   = (gridDim.x * 256) >> 6;

    for (int b = wid; b < NBLK; b += nw) {
        size_t base = (size_t)b * 128 + lane * 2;
        float2 v = *reinterpret_cast<const float2*>(x + base);
        float amax = fmaxf(fabsf(v.x), fabsf(v.y));
#pragma unroll
        for (int off = 32; off > 0; off >>= 1)
            amax = fmaxf(amax, __shfl_xor(amax, off));
        float s = amax * (1.0f / FP8_MAX);
        float q0 = 0.0f, q1 = 0.0f;
        if (s > 0.0f) {
            q0 = (float)__hip_fp8_e4m3(v.x / s) * s;
            q1 = (float)__hip_fp8_e4m3(v.y / s) * s;
        }
        __hip_bfloat162 o;
        o.x = __float2bfloat16(q0);
        o.y = __float2bfloat16(q1);
        *reinterpret_cast<__hip_bfloat162*>(xdq + base) = o;
    }
}

// ---------------------------------------------------------------------------
// Kernel 2: weight quant  w[N,K] f32 -> wdq[N,K] bf16
// ---------------------------------------------------------------------------
__global__ __launch_bounds__(256) void quant_w_kernel(
    const float* __restrict__ w, const float* __restrict__ ws,
    __hip_bfloat16* __restrict__ wdq)
{
    constexpr size_t NCHUNK = (size_t)Ndim * Kdim / 8;
    constexpr int CPR = Kdim / 8;
    constexpr int KB  = Kdim / 128;

    size_t idx    = (size_t)blockIdx.x * 256 + threadIdx.x;
    size_t stride = (size_t)gridDim.x * 256;

    for (size_t c = idx; c < NCHUNK; c += stride) {
        int n  = (int)(c / CPR);
        int kc = (int)(c - (size_t)n * CPR);
        int k  = kc * 8;
        float s = ws[(n >> 7) * KB + (k >> 7)];
        const float* src = w + (size_t)n * Kdim + k;
        float4 v0 = *reinterpret_cast<const float4*>(src);
        float4 v1 = *reinterpret_cast<const float4*>(src + 4);

        __hip_bfloat16 h[8];
        h[0] = __float2bfloat16((float)__hip_fp8_e4m3(v0.x) * s);
        h[1] = __float2bfloat16((float)__hip_fp8_e4m3(v0.y) * s);
        h[2] = __float2bfloat16((float)__hip_fp8_e4m3(v0.z) * s);
        h[3] = __float2bfloat16((float)__hip_fp8_e4m3(v0.w) * s);
        h[4] = __float2bfloat16((float)__hip_fp8_e4m3(v1.x) * s);
        h[5] = __float2bfloat16((float)__hip_fp8_e4m3(v1.y) * s);
        h[6] = __float2bfloat16((float)__hip_fp8_e4m3(v1.z) * s);
        h[7] = __float2bfloat16((float)__hip_fp8_e4m3(v1.w) * s);
        *reinterpret_cast<short8*>(wdq + (size_t)n * Kdim + k) =
            *reinterpret_cast<short8*>(h);
    }
}

// ---------------------------------------------------------------------------
// Kernel 3: 256x256 8-phase NT GEMM  C[M,N] f32 = A[M,K] @ B[N,K]^T  (bf16)
//
// Geometry: BM=BN=256, BK=64, 8 waves (2Mx4N), per-wave out 128x64.
// LDS 128 KiB = 2 buf x { A[2 halves][128][64], B[2 halves][128][64] } bf16.
//   region offsets (bytes, within buf*65536): A0=0, A1=16384, B0=32768, B1=49152
// st_16x32 swizzle: byte ^= ((byte>>9)&1)<<5 — applied on ds_read addr and
//   (inverse == same involution) on the global source of global_load_lds.
//
// Stage stream: half-tile j (tile T=j>>2, region map j&3: 0->B0 1->B1 2->A0
// 3->A1, buffer T&1) is issued at global phase g = j-6 (one per phase, 2
// global_load_lds calls/wave). Safety (proved per-region):
//   - same-buffer overwrites land only on B-halves at P2/P3; B-half reads
//     retire at P1 (last ds_read) + double barrier per phase.
//   - A-half overwrites are always for the other buffer.
// Boundary wait: vmcnt(4) per K-tile (2 newest half-tiles in flight),
// drains to vmcnt(0) for the last two tiles.
//
// Per-tile phases (each: reads, stage, BAR, setprio1, 16 MFMA, setprio0, BAR):
//   P0: read A[m0-3]x2ks (8) + B[n0-1]x2ks (4); Q0 = m0-3 x n0-1
//   P1: read B[n2-3]x2ks (4);                   Q1 = m0-3 x n2-3
//   P2: read A[m4-7]x2ks (8);                   Q2 = m4-7 x n0-1
//   P3: (no reads);                             Q3 = m4-7 x n2-3; vmcnt; BAR
// ---------------------------------------------------------------------------
constexpr int BM = 256, BN = 256, BK = 64;
constexpr int NT  = Kdim / BK;            // 112 K-tiles
constexpr int NBN = Ndim / BN;            // 64
constexpr int NWG = (Mdim / BM) * NBN;    // 1024 (%8 == 0)

__global__ __launch_bounds__(512, 2) void gemm256_kernel(
    const __hip_bfloat16* __restrict__ Ag,
    const __hip_bfloat16* __restrict__ Bg,
    float* __restrict__ C)
{
    extern __shared__ char smem[];   // 131072 bytes

    const int tid  = threadIdx.x;
    const int w    = tid >> 6;
    const int lane = tid & 63;
    const int wr   = w >> 2;          // 0..1
    const int wc   = w & 3;           // 0..3
    const int lr   = lane & 15;
    const int lk   = lane >> 4;

    // XCD-bijective block swizzle
    int bid = (int)blockIdx.x;
    int swz = (bid & 7) * (NWG >> 3) + (bid >> 3);
    const int bm = (swz / NBN) * BM;
    const int bn = (swz % NBN) * BN;

    // swizzled ds_read column offsets (bytes within a 128B row)
    const int sw   = ((lr >> 2) & 1) << 5;
    const int col0 = (lk * 16) ^ sw;         // ks = 0
    const int col1 = (64 + lk * 16) ^ sw;    // ks = 1
    const int bRow = (wc & 1) * 64;          // wave's row base in B region

    // staging per-thread constants: physical chunk -> logical (row, colbyte)
    int rowL[2], colB[2], ldsW[2];
#pragma unroll
    for (int q = 0; q < 2; ++q) {
        int chp = (w * 2 + q) * 64 + lane;           // 0..1023 (16B units)
        int chl = chp ^ (((chp >> 5) & 1) << 1);     // chunk-level st_16x32
        rowL[q] = chl >> 3;                          // 0..127
        colB[q] = (chl & 7) * 16;                    // byte col in row
        ldsW[q] = (w * 2 + q) * 1024;                // wave-uniform LDS slice
    }

    auto stage = [&](int j) {
        if (j >= 4 * NT) return;
        const int T    = j >> 2;
        const int r    = j & 3;          // 0:B0 1:B1 2:A0 3:A1
        const int isA  = r >> 1;
        const int half = r & 1;
        const int regByte = (T & 1) * 65536 + (isA ? 0 : 32768) + half * 16384;
        const __hip_bfloat16* base = isA ? Ag : Bg;
        const int rowBase = (isA ? bm : bn) + half * 128;
#pragma unroll
        for (int q = 0; q < 2; ++q) {
            const char* g = (const char*)(base + (size_t)(rowBase + rowL[q]) * Kdim + T * 64)
                            + colB[q];
            __builtin_amdgcn_global_load_lds((const AS1 void*)g,
                                             (AS3 void*)(smem + regByte + ldsW[q]),
                                             16, 0, 0);
        }
    };

    // ---- prologue: tile0 (all 4 halves) + tile1 (B0,B1) ----
    for (int j = 0; j < 6; ++j) stage(j);
    asm volatile("s_waitcnt vmcnt(4)" ::: "memory");
    BARRIER();

    f32x4 acc[8][4] = {};

    for (int t = 0; t < NT; ++t) {
        const int buf = t & 1;
        const char* aB = smem + buf * 65536 + wr * 16384;
        const char* bB = smem + buf * 65536 + 32768 + (wc >> 1) * 16384;
        short8 a0[4][2], a1[4][2], b0[2][2], b1[2][2];

        // ---------------- P0 ----------------
#pragma unroll
        for (int m = 0; m < 4; ++m) {
            const char* p = aB + (m * 16 + lr) * 128;
            a0[m][0] = *(const short8*)(p + col0);
            a0[m][1] = *(const short8*)(p + col1);
        }
#pragma unroll
        for (int n = 0; n < 2; ++n) {
            const char* p = bB + (bRow + n * 16 + lr) * 128;
            b0[n][0] = *(const short8*)(p + col0);
            b0[n][1] = *(const short8*)(p + col1);
        }
        stage(4 * t + 6);
        BARRIER();
        __builtin_amdgcn_s_setprio(1);
#pragma unroll
        for (int m = 0; m < 4; ++m)
#pragma unroll
            for (int n = 0; n < 2; ++n) {
                acc[m][n] = MFMA_BF16(a0[m][0], b0[n][0], acc[m][n], 0, 0, 0);
                acc[m][n] = MFMA_BF16(a0[m][1], b0[n][1], acc[m][n], 0, 0, 0);
            }
        __builtin_amdgcn_s_setprio(0);
        BARRIER();

        // ---------------- P1 ----------------
#pragma unroll
        for (int n = 0; n < 2; ++n) {
            const char* p = bB + (bRow + (n + 2) * 16 + lr) * 128;
            b1[n][0] = *(const short8*)(p + col0);
            b1[n][1] = *(const short8*)(p + col1);
        }
        stage(4 * t + 7);
        BARRIER();
        __builtin_amdgcn_s_setprio(1);
#pragma unroll
        for (int m = 0; m < 4; ++m)
#pragma unroll
            for (int n = 0; n < 2; ++n) {
                acc[m][n + 2] = MFMA_BF16(a0[m][0], b1[n][0], acc[m][n + 2], 0, 0, 0);
                acc[m][n + 2] = MFMA_BF16(a0[m][1], b1[n][1], acc[m][n + 2], 0, 0, 0);
            }
        __builtin_amdgcn_s_setprio(0);
        BARRIER();

        // ---------------- P2 ----------------
#pragma unroll
        for (int m = 0; m < 4; ++m) {
            const char* p = aB + ((m + 4) * 16 + lr) * 128;
            a1[m][0] = *(const short8*)(p + col0);
            a1[m][1] = *(const short8*)(p + col1);
        }
        stage(4 * t + 8);
        BARRIER();
        __builtin_amdgcn_s_setprio(1);
#pragma unroll
        for (int m = 0; m < 4; ++m)
#pragma unroll
            for (int n = 0; n < 2; ++n) {
                acc[m + 4][n] = MFMA_BF16(a1[m][0], b0[n][0], acc[m + 4][n], 0, 0, 0);
                acc[m + 4][n] = MFMA_BF16(a1[m][1], b0[n][1], acc[m + 4][n], 0, 0, 0);
            }
        __builtin_amdgcn_s_setprio(0);
        BARRIER();

        // ---------------- P3 ----------------
        stage(4 * t + 9);
        BARRIER();
        __builtin_amdgcn_s_setprio(1);
#pragma unroll
        for (int m = 0; m < 4; ++m)
#pragma unroll
            for (int n = 0; n < 2; ++n) {
                acc[m + 4][n + 2] = MFMA_BF16(a1[m][0], b1[n][0], acc[m + 4][n + 2], 0, 0, 0);
                acc[m + 4][n + 2] = MFMA_BF16(a1[m][1], b1[n][1], acc[m + 4][n + 2], 0, 0, 0);
            }
        __builtin_amdgcn_s_setprio(0);
        if (t < NT - 2) { asm volatile("s_waitcnt vmcnt(4)" ::: "memory"); }
        else            { asm volatile("s_waitcnt vmcnt(0)" ::: "memory"); }
        BARRIER();
    }

    // ---- epilogue: C/D layout col = lr, row = lk*4 + j ----
#pragma unroll
    for (int m = 0; m < 8; ++m) {
#pragma unroll
        for (int n = 0; n < 4; ++n) {
            const int row0 = bm + wr * 128 + m * 16 + lk * 4;
            const int col  = bn + wc * 64 + n * 16 + lr;
#pragma unroll
            for (int j = 0; j < 4; ++j)
                C[(size_t)(row0 + j) * Ndim + col] = acc[m][n][j];
        }
    }
}

// ---------------------------------------------------------------------------
extern "C" void kernel_launch(void* const* d_in, const int* in_sizes, int n_in,
                              void* d_out, int out_size, void* d_ws, size_t ws_size,
                              hipStream_t stream) {
    const float* x  = (const float*)d_in[0];
    const float* w  = (const float*)d_in[1];
    const float* ws = (const float*)d_in[2];

    __hip_bfloat16* xdq = (__hip_bfloat16*)d_ws;
    __hip_bfloat16* wdq = xdq + (size_t)Mdim * Kdim;

    quant_x_kernel<<<2048, 256, 0, stream>>>(x, xdq);
    quant_w_kernel<<<4096, 256, 0, stream>>>(w, ws, wdq);

    hipFuncSetAttribute((const void*)gemm256_kernel,
                        hipFuncAttributeMaxDynamicSharedMemorySize, 131072);
    gemm256_kernel<<<NWG, 512, 131072, stream>>>(xdq, wdq, (float*)d_out);
}

// Round 3
// 981.205 us; speedup vs baseline: 1.7450x; 1.0604x over previous
//
#include <hip/hip_runtime.h>
#include <hip/hip_bf16.h>
#include <hip/hip_fp8.h>

typedef __attribute__((ext_vector_type(8))) short short8;
typedef __attribute__((ext_vector_type(4))) float f32x4;

#define AS1 __attribute__((address_space(1)))
#define AS3 __attribute__((address_space(3)))

static constexpr int Mdim = 4096;
static constexpr int Kdim = 7168;
static constexpr int Ndim = 16384;
static constexpr float FP8_MAX = 448.0f;

// compiler-fence + raw barrier (no implicit vmcnt(0) drain)
#define BARRIER() do { asm volatile("" ::: "memory"); \
                       __builtin_amdgcn_s_barrier();  \
                       asm volatile("" ::: "memory"); } while (0)

#define MFMA_BF16 __builtin_amdgcn_mfma_f32_16x16x32_bf16

// ---------------------------------------------------------------------------
// Kernel 1: activation quant  x[M,K] f32 -> xdq[M,K] bf16 (per 1x128 block)
// ---------------------------------------------------------------------------
__global__ __launch_bounds__(256) void quant_x_kernel(
    const float* __restrict__ x, __hip_bfloat16* __restrict__ xdq)
{
    constexpr int NBLK = Mdim * (Kdim / 128);
    const int lane = threadIdx.x & 63;
    const int wid  = (blockIdx.x * 256 + threadIdx.x) >> 6;
    const int nw   = (gridDim.x * 256) >> 6;

    for (int b = wid; b < NBLK; b += nw) {
        size_t base = (size_t)b * 128 + lane * 2;
        float2 v = *reinterpret_cast<const float2*>(x + base);
        float amax = fmaxf(fabsf(v.x), fabsf(v.y));
#pragma unroll
        for (int off = 32; off > 0; off >>= 1)
            amax = fmaxf(amax, __shfl_xor(amax, off));
        float s = amax * (1.0f / FP8_MAX);
        float q0 = 0.0f, q1 = 0.0f;
        if (s > 0.0f) {
            q0 = (float)__hip_fp8_e4m3(v.x / s) * s;
            q1 = (float)__hip_fp8_e4m3(v.y / s) * s;
        }
        __hip_bfloat162 o;
        o.x = __float2bfloat16(q0);
        o.y = __float2bfloat16(q1);
        *reinterpret_cast<__hip_bfloat162*>(xdq + base) = o;
    }
}

// ---------------------------------------------------------------------------
// Kernel 2: weight quant  w[N,K] f32 -> wdq[N,K] bf16
// ---------------------------------------------------------------------------
__global__ __launch_bounds__(256) void quant_w_kernel(
    const float* __restrict__ w, const float* __restrict__ ws,
    __hip_bfloat16* __restrict__ wdq)
{
    constexpr size_t NCHUNK = (size_t)Ndim * Kdim / 8;
    constexpr int CPR = Kdim / 8;
    constexpr int KB  = Kdim / 128;

    size_t idx    = (size_t)blockIdx.x * 256 + threadIdx.x;
    size_t stride = (size_t)gridDim.x * 256;

    for (size_t c = idx; c < NCHUNK; c += stride) {
        int n  = (int)(c / CPR);
        int kc = (int)(c - (size_t)n * CPR);
        int k  = kc * 8;
        float s = ws[(n >> 7) * KB + (k >> 7)];
        const float* src = w + (size_t)n * Kdim + k;
        float4 v0 = *reinterpret_cast<const float4*>(src);
        float4 v1 = *reinterpret_cast<const float4*>(src + 4);

        __hip_bfloat16 h[8];
        h[0] = __float2bfloat16((float)__hip_fp8_e4m3(v0.x) * s);
        h[1] = __float2bfloat16((float)__hip_fp8_e4m3(v0.y) * s);
        h[2] = __float2bfloat16((float)__hip_fp8_e4m3(v0.z) * s);
        h[3] = __float2bfloat16((float)__hip_fp8_e4m3(v0.w) * s);
        h[4] = __float2bfloat16((float)__hip_fp8_e4m3(v1.x) * s);
        h[5] = __float2bfloat16((float)__hip_fp8_e4m3(v1.y) * s);
        h[6] = __float2bfloat16((float)__hip_fp8_e4m3(v1.z) * s);
        h[7] = __float2bfloat16((float)__hip_fp8_e4m3(v1.w) * s);
        *reinterpret_cast<short8*>(wdq + (size_t)n * Kdim + k) =
            *reinterpret_cast<short8*>(h);
    }
}

// ---------------------------------------------------------------------------
// Kernel 3: 256x256 8-phase NT GEMM  C[M,N] f32 = A[M,K] @ B[N,K]^T  (bf16)
//
// Geometry: BM=BN=256, BK=64, 8 waves (2Mx4N), per-wave out 128x64.
// LDS 128 KiB = 2 buf x { A[2 halves][128][64], B[2 halves][128][64] } bf16.
//   region offsets (bytes, within buf*65536): A0=0, A1=16384, B0=32768, B1=49152
//
// Swizzle (G4/m214 3-bit XOR — regions are row-major [128 rows][128 B], so a
// row covers all 32 banks and bank = f(col) only; 16 lanes at same col would
// be 16-way):  phys_byte = row*128 + (logical_col ^ ((row&7)<<4)).
// Applied on ds_read addr AND (same involution) on the global source of
// global_load_lds (LDS dest stays linear — rule #21).
//
// Stage stream: half-tile j (tile T=j>>2, region map j&3: 0->B0 1->B1 2->A0
// 3->A1, buffer T&1) is issued at global phase g = j-6 (one per phase, 2
// global_load_lds calls/wave). Safety: same-buffer overwrites land only on
// B-halves at P2/P3; B-half reads retire at P1; A-half overwrites always
// cross-buffer. Boundary wait: vmcnt(4) per K-tile, drain to 0 at the end.
// ---------------------------------------------------------------------------
constexpr int BM = 256, BN = 256, BK = 64;
constexpr int NT  = Kdim / BK;            // 112 K-tiles
constexpr int NBN = Ndim / BN;            // 64
constexpr int NWG = (Mdim / BM) * NBN;    // 1024 (%8 == 0)

__global__ __launch_bounds__(512, 2) void gemm256_kernel(
    const __hip_bfloat16* __restrict__ Ag,
    const __hip_bfloat16* __restrict__ Bg,
    float* __restrict__ C)
{
    extern __shared__ char smem[];   // 131072 bytes

    const int tid  = threadIdx.x;
    const int w    = tid >> 6;
    const int lane = tid & 63;
    const int wr   = w >> 2;          // 0..1
    const int wc   = w & 3;           // 0..3
    const int lr   = lane & 15;
    const int lk   = lane >> 4;

    // XCD-bijective block swizzle
    int bid = (int)blockIdx.x;
    int swz = (bid & 7) * (NWG >> 3) + (bid >> 3);
    const int bm = (swz / NBN) * BM;
    const int bn = (swz % NBN) * BN;

    // swizzled ds_read column offsets (bytes within a 128B row)
    // fragment rows are (16*m + lr) and (bRow + 16*n + lr) with bRow%8==0,
    // so row&7 == lr&7 for every read.
    const int sw   = (lr & 7) << 4;
    const int col0 = (lk * 16) ^ sw;         // ks = 0
    const int col1 = (64 + lk * 16) ^ sw;    // ks = 1
    const int bRow = (wc & 1) * 64;          // wave's row base in B region

    // staging per-thread constants: phys 16B chunk -> logical (row, colbyte)
    // phys chunk chp: row = chp>>3, slot = chp&7; logical slot = slot^(row&7)
    int rowL[2], colB[2], ldsW[2];
#pragma unroll
    for (int q = 0; q < 2; ++q) {
        int chp = (w * 2 + q) * 64 + lane;           // 0..1023 (16B units)
        rowL[q] = chp >> 3;                          // 0..127
        colB[q] = ((chp & 7) ^ (rowL[q] & 7)) * 16;  // swizzled byte col
        ldsW[q] = (w * 2 + q) * 1024;                // wave-uniform LDS slice
    }

    auto stage = [&](int j) {
        if (j >= 4 * NT) return;
        const int T    = j >> 2;
        const int r    = j & 3;          // 0:B0 1:B1 2:A0 3:A1
        const int isA  = r >> 1;
        const int half = r & 1;
        const int regByte = (T & 1) * 65536 + (isA ? 0 : 32768) + half * 16384;
        const __hip_bfloat16* base = isA ? Ag : Bg;
        const int rowBase = (isA ? bm : bn) + half * 128;
#pragma unroll
        for (int q = 0; q < 2; ++q) {
            const char* g = (const char*)(base + (size_t)(rowBase + rowL[q]) * Kdim + T * 64)
                            + colB[q];
            __builtin_amdgcn_global_load_lds((const AS1 void*)g,
                                             (AS3 void*)(smem + regByte + ldsW[q]),
                                             16, 0, 0);
        }
    };

    // ---- prologue: tile0 (all 4 halves) + tile1 (B0,B1) ----
    for (int j = 0; j < 6; ++j) stage(j);
    asm volatile("s_waitcnt vmcnt(4)" ::: "memory");
    BARRIER();

    f32x4 acc[8][4] = {};

    for (int t = 0; t < NT; ++t) {
        const int buf = t & 1;
        const char* aB = smem + buf * 65536 + wr * 16384;
        const char* bB = smem + buf * 65536 + 32768 + (wc >> 1) * 16384;
        short8 a0[4][2], a1[4][2], b0[2][2], b1[2][2];

        // ---------------- P0 ----------------
#pragma unroll
        for (int m = 0; m < 4; ++m) {
            const char* p = aB + (m * 16 + lr) * 128;
            a0[m][0] = *(const short8*)(p + col0);
            a0[m][1] = *(const short8*)(p + col1);
        }
#pragma unroll
        for (int n = 0; n < 2; ++n) {
            const char* p = bB + (bRow + n * 16 + lr) * 128;
            b0[n][0] = *(const short8*)(p + col0);
            b0[n][1] = *(const short8*)(p + col1);
        }
        stage(4 * t + 6);
        BARRIER();
        __builtin_amdgcn_s_setprio(1);
#pragma unroll
        for (int m = 0; m < 4; ++m)
#pragma unroll
            for (int n = 0; n < 2; ++n) {
                acc[m][n] = MFMA_BF16(a0[m][0], b0[n][0], acc[m][n], 0, 0, 0);
                acc[m][n] = MFMA_BF16(a0[m][1], b0[n][1], acc[m][n], 0, 0, 0);
            }
        __builtin_amdgcn_s_setprio(0);
        BARRIER();

        // ---------------- P1 ----------------
#pragma unroll
        for (int n = 0; n < 2; ++n) {
            const char* p = bB + (bRow + (n + 2) * 16 + lr) * 128;
            b1[n][0] = *(const short8*)(p + col0);
            b1[n][1] = *(const short8*)(p + col1);
        }
        stage(4 * t + 7);
        BARRIER();
        __builtin_amdgcn_s_setprio(1);
#pragma unroll
        for (int m = 0; m < 4; ++m)
#pragma unroll
            for (int n = 0; n < 2; ++n) {
                acc[m][n + 2] = MFMA_BF16(a0[m][0], b1[n][0], acc[m][n + 2], 0, 0, 0);
                acc[m][n + 2] = MFMA_BF16(a0[m][1], b1[n][1], acc[m][n + 2], 0, 0, 0);
            }
        __builtin_amdgcn_s_setprio(0);
        BARRIER();

        // ---------------- P2 ----------------
#pragma unroll
        for (int m = 0; m < 4; ++m) {
            const char* p = aB + ((m + 4) * 16 + lr) * 128;
            a1[m][0] = *(const short8*)(p + col0);
            a1[m][1] = *(const short8*)(p + col1);
        }
        stage(4 * t + 8);
        BARRIER();
        __builtin_amdgcn_s_setprio(1);
#pragma unroll
        for (int m = 0; m < 4; ++m)
#pragma unroll
            for (int n = 0; n < 2; ++n) {
                acc[m + 4][n] = MFMA_BF16(a1[m][0], b0[n][0], acc[m + 4][n], 0, 0, 0);
                acc[m + 4][n] = MFMA_BF16(a1[m][1], b0[n][1], acc[m + 4][n], 0, 0, 0);
            }
        __builtin_amdgcn_s_setprio(0);
        BARRIER();

        // ---------------- P3 ----------------
        stage(4 * t + 9);
        BARRIER();
        __builtin_amdgcn_s_setprio(1);
#pragma unroll
        for (int m = 0; m < 4; ++m)
#pragma unroll
            for (int n = 0; n < 2; ++n) {
                acc[m + 4][n + 2] = MFMA_BF16(a1[m][0], b1[n][0], acc[m + 4][n + 2], 0, 0, 0);
                acc[m + 4][n + 2] = MFMA_BF16(a1[m][1], b1[n][1], acc[m + 4][n + 2], 0, 0, 0);
            }
        __builtin_amdgcn_s_setprio(0);
        if (t < NT - 2) { asm volatile("s_waitcnt vmcnt(4)" ::: "memory"); }
        else            { asm volatile("s_waitcnt vmcnt(0)" ::: "memory"); }
        BARRIER();
    }

    // ---- epilogue: C/D layout col = lr, row = lk*4 + j ----
#pragma unroll
    for (int m = 0; m < 8; ++m) {
#pragma unroll
        for (int n = 0; n < 4; ++n) {
            const int row0 = bm + wr * 128 + m * 16 + lk * 4;
            const int col  = bn + wc * 64 + n * 16 + lr;
#pragma unroll
            for (int j = 0; j < 4; ++j)
                C[(size_t)(row0 + j) * Ndim + col] = acc[m][n][j];
        }
    }
}

// ---------------------------------------------------------------------------
extern "C" void kernel_launch(void* const* d_in, const int* in_sizes, int n_in,
                              void* d_out, int out_size, void* d_ws, size_t ws_size,
                              hipStream_t stream) {
    const float* x  = (const float*)d_in[0];
    const float* w  = (const float*)d_in[1];
    const float* ws = (const float*)d_in[2];

    __hip_bfloat16* xdq = (__hip_bfloat16*)d_ws;
    __hip_bfloat16* wdq = xdq + (size_t)Mdim * Kdim;

    quant_x_kernel<<<2048, 256, 0, stream>>>(x, xdq);
    quant_w_kernel<<<4096, 256, 0, stream>>>(w, ws, wdq);

    hipFuncSetAttribute((const void*)gemm256_kernel,
                        hipFuncAttributeMaxDynamicSharedMemorySize, 131072);
    gemm256_kernel<<<NWG, 512, 131072, stream>>>(xdq, wdq, (float*)d_out);
}